// Round 3
// baseline (505.742 us; speedup 1.0000x reference)
//
#include <hip/hip_runtime.h>
#include <hip/hip_cooperative_groups.h>

namespace cg = cooperative_groups;

#define DIM_IN 128
#define DIM_HID 256
#define DIM_OUT 128
#define N_DIST 1024
#define NB 256          // blocks for the cooperative sort kernel (1 per CU)
#define CHUNK_MAX 2048  // per-block node chunk cached in LDS (n/NB = 1954)

// ws layout (bytes):
// [0,      4096): counts[1024]
// [4096,   8192): offsets[1024]   (published by sort block 0, read by district)
// [65536, 65536+1MB): blockHist -> rewritten in place (phase B) to per-district
//                     exclusive block starts (WITHOUT global offset)
// [2MB,    4MB): sorted node indices [N] int32
//
// No global atomics anywhere: deterministic counting sort.

__device__ __forceinline__ int detect_is64(const int* __restrict__ zone_raw,
                                           int t, int* s_flag) {
    // int64 zone_lst => high words all zero. Checked by wave 0 via ballot.
    if (t < 64) {
        bool hi_zero = (zone_raw[2 * t + 1] == 0);
        unsigned long long m = __ballot(hi_zero);
        if (t == 0) *s_flag = (m == ~0ull) ? 1 : 0;
    }
    __syncthreads();
    return *s_flag;
}

// One cooperative kernel replacing hist + scanA + scatter.
// Phase A: per-block histogram; decoded district ids cached in LDS (ushort).
// Phase B: per-district prefix over the NB block histograms (4 districts/blk).
// Phase C: redundant per-block exclusive scan of counts -> offsets, then
//          LDS-atomic scatter from the cached ids. Block 0 publishes offsets.
__global__ __launch_bounds__(256)
void sort_kernel(const int* __restrict__ zone, int n,
                 int* __restrict__ blockHist,
                 int* __restrict__ counts,
                 int* __restrict__ offsets,
                 int* __restrict__ sorted) {
    cg::grid_group grid = cg::this_grid();
    __shared__ int lhist[N_DIST];
    __shared__ int lcur[N_DIST];            // reused as off-source too
    __shared__ unsigned short zc[CHUNK_MAX];
    __shared__ int wsum[4];
    __shared__ int s_is64;

    const int t = threadIdx.x;
    const int b = blockIdx.x;
    const int lane = t & 63;
    const int w = t >> 6;

    for (int i = t; i < N_DIST; i += 256) lhist[i] = 0;
    const int is64 = detect_is64(zone, t, &s_is64);   // __syncthreads inside

    const int chunk = (n + NB - 1) / NB;
    const int start = b * chunk;
    const int end = min(n, start + chunk);
    const bool cache_ok = (chunk <= CHUNK_MAX);
    const long long* zone64 = (const long long*)zone;

    // ---- phase A: histogram + id cache ----
    for (int i = start + t; i < end; i += 256) {
        int z = is64 ? (int)zone64[i] : zone[i];
        if (cache_ok) zc[i - start] = (unsigned short)z;
        atomicAdd(&lhist[z], 1);            // LDS atomic only
    }
    __syncthreads();
    for (int i = t; i < N_DIST; i += 256) blockHist[b * N_DIST + i] = lhist[i];

    __threadfence();
    grid.sync();

    // ---- phase B: per-district block-prefix (this block owns d = 4b+w) ----
    {
        const int d = b * 4 + w;
        int v0 = blockHist[(4 * lane + 0) * N_DIST + d];
        int v1 = blockHist[(4 * lane + 1) * N_DIST + d];
        int v2 = blockHist[(4 * lane + 2) * N_DIST + d];
        int v3 = blockHist[(4 * lane + 3) * N_DIST + d];
        const int tsum = v0 + v1 + v2 + v3;

        int s = tsum;                       // inclusive wave scan of lane sums
#pragma unroll
        for (int off = 1; off < 64; off <<= 1) {
            int u = __shfl_up(s, off);
            if (lane >= off) s += u;
        }
        const int total = __shfl(s, 63);
        int excl = s - tsum;

        blockHist[(4 * lane + 0) * N_DIST + d] = excl; excl += v0;
        blockHist[(4 * lane + 1) * N_DIST + d] = excl; excl += v1;
        blockHist[(4 * lane + 2) * N_DIST + d] = excl; excl += v2;
        blockHist[(4 * lane + 3) * N_DIST + d] = excl;

        if (lane == 0) counts[d] = total;
    }

    __threadfence();
    grid.sync();

    // ---- phase C: offsets scan (redundant per block) + scatter ----
    {
        int4 c4 = ((const int4*)counts)[t];     // thread t owns counts[4t..4t+3]
        const int tsum = c4.x + c4.y + c4.z + c4.w;
        int s = tsum;
#pragma unroll
        for (int o = 1; o < 64; o <<= 1) {
            int u = __shfl_up(s, o);
            if (lane >= o) s += u;
        }
        if (lane == 63) wsum[w] = s;
        __syncthreads();
        int wbase = 0;
#pragma unroll
        for (int ww = 0; ww < 3; ww++) wbase += (ww < w) ? wsum[ww] : 0;
        int excl = wbase + s - tsum;
        // off[] lives in lhist's storage (reuse): exclusive district offsets
        lhist[4 * t + 0] = excl;
        lhist[4 * t + 1] = excl + c4.x;
        lhist[4 * t + 2] = excl + c4.x + c4.y;
        lhist[4 * t + 3] = excl + c4.x + c4.y + c4.z;
        __syncthreads();

        for (int i = t; i < N_DIST; i += 256)
            lcur[i] = lhist[i] + blockHist[b * N_DIST + i];
        if (b == 0)
            for (int i = t; i < N_DIST; i += 256) offsets[i] = lhist[i];
        __syncthreads();

        for (int i = start + t; i < end; i += 256) {
            int z = cache_ok ? (int)zc[i - start]
                             : (is64 ? (int)zone64[i] : zone[i]);
            int pos = atomicAdd(&lcur[z], 1);   // LDS atomic only
            sorted[pos] = i;
        }
    }
}

// One block (512 threads) per district: 16 node-groups x 32 lanes gather
// float4 rows; staged sorted indices in LDS; reduce to head[128]; fused MLP
// with both linear layers split across all 512 threads (LDS partial combine).
#define NG 16
__global__ __launch_bounds__(512)
void district_kernel(const float* __restrict__ x, const int* __restrict__ sorted,
                     const int* __restrict__ offsets, const int* __restrict__ counts,
                     const float* __restrict__ w1, const float* __restrict__ b1,
                     const float* __restrict__ w2, const float* __restrict__ b2,
                     float* __restrict__ out) {
    const int d = blockIdx.x;
    const int start = offsets[d];
    const int cnt = counts[d];
    const int t = threadIdx.x;
    const int q = t & 31;   // 4-float chunk index: dims [4q, 4q+4)
    const int g = t >> 5;   // node group 0..15

    __shared__ int sidx[1024];

    const float* xq = x + (size_t)q * 4;
    float4 a0 = make_float4(0.f, 0.f, 0.f, 0.f);
    float4 a1 = a0, a2 = a0, a3 = a0;

    for (int base = 0; base < cnt; base += 1024) {
        const int m = min(cnt - base, 1024);
        for (int i = t; i < m; i += 512) sidx[i] = sorted[start + base + i];
        __syncthreads();

        int n = g;
        for (; n + 3 * NG < m; n += 4 * NG) {
            int i0 = sidx[n];
            int i1 = sidx[n + NG];
            int i2 = sidx[n + 2 * NG];
            int i3 = sidx[n + 3 * NG];
            float4 v0 = *(const float4*)(xq + (size_t)i0 * DIM_IN);
            float4 v1 = *(const float4*)(xq + (size_t)i1 * DIM_IN);
            float4 v2 = *(const float4*)(xq + (size_t)i2 * DIM_IN);
            float4 v3 = *(const float4*)(xq + (size_t)i3 * DIM_IN);
            a0.x += v0.x; a0.y += v0.y; a0.z += v0.z; a0.w += v0.w;
            a1.x += v1.x; a1.y += v1.y; a1.z += v1.z; a1.w += v1.w;
            a2.x += v2.x; a2.y += v2.y; a2.z += v2.z; a2.w += v2.w;
            a3.x += v3.x; a3.y += v3.y; a3.z += v3.z; a3.w += v3.w;
        }
        for (; n < m; n += NG) {
            int i0 = sidx[n];
            float4 v0 = *(const float4*)(xq + (size_t)i0 * DIM_IN);
            a0.x += v0.x; a0.y += v0.y; a0.z += v0.z; a0.w += v0.w;
        }
        __syncthreads();   // protect sidx before next chunk refill
    }

    a0.x += a1.x + a2.x + a3.x;
    a0.y += a1.y + a2.y + a3.y;
    a0.z += a1.z + a2.z + a3.z;
    a0.w += a1.w + a2.w + a3.w;

    __shared__ float part[NG][DIM_IN];
    part[g][q * 4 + 0] = a0.x;
    part[g][q * 4 + 1] = a0.y;
    part[g][q * 4 + 2] = a0.z;
    part[g][q * 4 + 3] = a0.w;
    __syncthreads();

    __shared__ float hrelu[DIM_IN];
    if (t < DIM_IN) {
        float s = 0.f;
#pragma unroll
        for (int gg = 0; gg < NG; gg++) s += part[gg][t];
        hrelu[t] = fmaxf(s, 0.f);
    }
    __syncthreads();

    // layer 1: h1[c] = relu(b1[c] + sum_k hrelu[k]*w1[k,c]); w1 [128,256]
    // split k-range in 2 halves across the 512 threads
    {
        const int c = t & 255;
        const int h = t >> 8;      // 0..1
        float s1 = 0.f;
        const int k0 = h * 64;
#pragma unroll 8
        for (int k = k0; k < k0 + 64; k++) {
            s1 = fmaf(hrelu[k], w1[k * DIM_HID + c], s1);
        }
        __shared__ float p1[2][DIM_HID];
        p1[h][c] = s1;
        __syncthreads();
        __shared__ float h1s[DIM_HID];
        if (t < DIM_HID) h1s[t] = fmaxf(b1[t] + p1[0][t] + p1[1][t], 0.f);
        __syncthreads();

        // layer 2: out[c2] = b2[c2] + sum_j h1[j]*w2[j,c2]; w2 [256,128]
        // split j-range in 4 quarters across the 512 threads
        const int c2 = t & 127;
        const int hh = t >> 7;     // 0..3
        float s2 = 0.f;
        const int j0 = hh * 64;
#pragma unroll 8
        for (int j = j0; j < j0 + 64; j++) {
            s2 = fmaf(h1s[j], w2[j * DIM_OUT + c2], s2);
        }
        __shared__ float p2[4][DIM_OUT];
        p2[hh][c2] = s2;
        __syncthreads();
        if (t < DIM_OUT)
            out[d * DIM_OUT + t] =
                b2[t] + p2[0][t] + p2[1][t] + p2[2][t] + p2[3][t];
    }
}

extern "C" void kernel_launch(void* const* d_in, const int* in_sizes, int n_in,
                              void* d_out, int out_size, void* d_ws, size_t ws_size,
                              hipStream_t stream) {
    const float* x    = (const float*)d_in[0];
    const int*   zone = (const int*)d_in[1];
    const float* w1   = (const float*)d_in[2];
    const float* b1   = (const float*)d_in[3];
    const float* w2   = (const float*)d_in[4];
    const float* b2   = (const float*)d_in[5];
    float* out = (float*)d_out;
    int n = in_sizes[0] / DIM_IN;   // 500000 nodes

    char* ws = (char*)d_ws;
    int* counts    = (int*)(ws);
    int* offsets   = (int*)(ws + 4096);
    int* blockHist = (int*)(ws + 65536);
    int* sorted    = (int*)(ws + (2u << 20));

    void* args[] = { (void*)&zone, (void*)&n, (void*)&blockHist,
                     (void*)&counts, (void*)&offsets, (void*)&sorted };
    hipLaunchCooperativeKernel((const void*)sort_kernel, dim3(NB), dim3(256),
                               args, 0, stream);
    district_kernel<<<N_DIST, 512, 0, stream>>>(x, sorted, offsets, counts,
                                                w1, b1, w2, b2, out);
}

// Round 4
// 435.322 us; speedup vs baseline: 1.1618x; 1.1618x over previous
//
#include <hip/hip_runtime.h>

#define DIM_IN 128
#define DIM_HID 256
#define DIM_OUT 128
#define N_DIST 1024
#define NB 256          // blocks for the fused sort kernel (<= 1 per CU, all co-resident)
#define CHUNK_MAX 2048  // per-block node chunk cached in LDS (n/NB = 1954)

// ws layout (bytes):
// [0,      4096): counts[1024]
// [4096,   8192): offsets[1024]   (published by sort block 0, read by district)
// [8192,   8256): grid-barrier counter (zeroed via hipMemsetAsync each launch)
// [65536, 65536+1MB): blockHist -> rewritten in place (phase B) to per-district
//                     exclusive block starts (WITHOUT global offset)
// [2MB,    4MB): sorted node indices [N] int32
//
// No data-carrying global atomics: deterministic counting sort. The only
// global atomic is the barrier arrival counter (sync-only, not data).

typedef float f32x4 __attribute__((ext_vector_type(4)));

__device__ __forceinline__ int detect_is64(const int* __restrict__ zone_raw,
                                           int t, int* s_flag) {
    // int64 zone_lst => high words all zero. Checked by wave 0 via ballot.
    if (t < 64) {
        bool hi_zero = (zone_raw[2 * t + 1] == 0);
        unsigned long long m = __ballot(hi_zero);
        if (t == 0) *s_flag = (m == ~0ull) ? 1 : 0;
    }
    __syncthreads();
    return *s_flag;
}

// Hand-rolled grid barrier: monotonic counter, no reset needed within launch.
// All NB blocks are co-resident (65536 threads << 524288 capacity) => no
// deadlock. Release: __threadfence before arrival. Acquire: agent-scope
// acquire load in the spin + __threadfence after the wait.
__device__ __forceinline__ void grid_barrier(int* __restrict__ bar, int target,
                                             int t) {
    __syncthreads();
    if (t == 0) {
        __threadfence();   // release: make this block's writes device-visible
        __hip_atomic_fetch_add(bar, 1, __ATOMIC_RELEASE,
                               __HIP_MEMORY_SCOPE_AGENT);
        while (__hip_atomic_load(bar, __ATOMIC_ACQUIRE,
                                 __HIP_MEMORY_SCOPE_AGENT) < target) {
            __builtin_amdgcn_s_sleep(1);
        }
    }
    __syncthreads();
    __threadfence();       // acquire: invalidate stale local caches
}

// One fused kernel replacing hist + scanA + scatter (regular launch, not coop).
// Phase A: per-block histogram; decoded district ids cached in LDS (ushort).
// Phase B: per-district prefix over the NB block histograms (4 districts/blk).
// Phase C: redundant per-block exclusive scan of counts -> offsets, then
//          LDS-atomic scatter from the cached ids. Block 0 publishes offsets.
__global__ __launch_bounds__(256)
void sort_kernel(const int* __restrict__ zone, int n,
                 int* __restrict__ blockHist,
                 int* __restrict__ counts,
                 int* __restrict__ offsets,
                 int* __restrict__ sorted,
                 int* __restrict__ bar) {
    __shared__ int lhist[N_DIST];
    __shared__ int lcur[N_DIST];
    __shared__ unsigned short zc[CHUNK_MAX];
    __shared__ int wsum[4];
    __shared__ int s_is64;

    const int t = threadIdx.x;
    const int b = blockIdx.x;
    const int lane = t & 63;
    const int w = t >> 6;

    for (int i = t; i < N_DIST; i += 256) lhist[i] = 0;
    const int is64 = detect_is64(zone, t, &s_is64);   // __syncthreads inside

    const int chunk = (n + NB - 1) / NB;
    const int start = b * chunk;
    const int end = min(n, start + chunk);
    const bool cache_ok = (chunk <= CHUNK_MAX);
    const long long* zone64 = (const long long*)zone;

    // ---- phase A: histogram + id cache ----
    for (int i = start + t; i < end; i += 256) {
        int z = is64 ? (int)zone64[i] : zone[i];
        if (cache_ok) zc[i - start] = (unsigned short)z;
        atomicAdd(&lhist[z], 1);            // LDS atomic only
    }
    __syncthreads();
    for (int i = t; i < N_DIST; i += 256) blockHist[b * N_DIST + i] = lhist[i];

    grid_barrier(bar, NB, t);

    // ---- phase B: per-district block-prefix (this block owns d = 4b+w) ----
    {
        const int d = b * 4 + w;
        int v0 = blockHist[(4 * lane + 0) * N_DIST + d];
        int v1 = blockHist[(4 * lane + 1) * N_DIST + d];
        int v2 = blockHist[(4 * lane + 2) * N_DIST + d];
        int v3 = blockHist[(4 * lane + 3) * N_DIST + d];
        const int tsum = v0 + v1 + v2 + v3;

        int s = tsum;                       // inclusive wave scan of lane sums
#pragma unroll
        for (int off = 1; off < 64; off <<= 1) {
            int u = __shfl_up(s, off);
            if (lane >= off) s += u;
        }
        const int total = __shfl(s, 63);
        int excl = s - tsum;

        blockHist[(4 * lane + 0) * N_DIST + d] = excl; excl += v0;
        blockHist[(4 * lane + 1) * N_DIST + d] = excl; excl += v1;
        blockHist[(4 * lane + 2) * N_DIST + d] = excl; excl += v2;
        blockHist[(4 * lane + 3) * N_DIST + d] = excl;

        if (lane == 0) counts[d] = total;
    }

    grid_barrier(bar, 2 * NB, t);

    // ---- phase C: offsets scan (redundant per block) + scatter ----
    {
        int4 c4 = ((const int4*)counts)[t];     // thread t owns counts[4t..4t+3]
        const int tsum = c4.x + c4.y + c4.z + c4.w;
        int s = tsum;
#pragma unroll
        for (int o = 1; o < 64; o <<= 1) {
            int u = __shfl_up(s, o);
            if (lane >= o) s += u;
        }
        if (lane == 63) wsum[w] = s;
        __syncthreads();
        int wbase = 0;
#pragma unroll
        for (int ww = 0; ww < 3; ww++) wbase += (ww < w) ? wsum[ww] : 0;
        int excl = wbase + s - tsum;
        // off[] reuses lhist storage: exclusive district offsets
        lhist[4 * t + 0] = excl;
        lhist[4 * t + 1] = excl + c4.x;
        lhist[4 * t + 2] = excl + c4.x + c4.y;
        lhist[4 * t + 3] = excl + c4.x + c4.y + c4.z;
        __syncthreads();

        for (int i = t; i < N_DIST; i += 256)
            lcur[i] = lhist[i] + blockHist[b * N_DIST + i];
        if (b == 0)
            for (int i = t; i < N_DIST; i += 256) offsets[i] = lhist[i];
        __syncthreads();

        for (int i = start + t; i < end; i += 256) {
            int z = cache_ok ? (int)zc[i - start]
                             : (is64 ? (int)zone64[i] : zone[i]);
            int pos = atomicAdd(&lcur[z], 1);   // LDS atomic only
            sorted[pos] = i;
        }
    }
}

// One block (512 threads) per district: 16 node-groups x 32 lanes gather
// float4 rows (nontemporal: x is read-once, keep L2 for weights); staged
// sorted indices in LDS; reduce to head[128]; fused MLP with both linear
// layers split across all 512 threads (LDS partial combine).
#define NG 16
__global__ __launch_bounds__(512)
void district_kernel(const float* __restrict__ x, const int* __restrict__ sorted,
                     const int* __restrict__ offsets, const int* __restrict__ counts,
                     const float* __restrict__ w1, const float* __restrict__ b1,
                     const float* __restrict__ w2, const float* __restrict__ b2,
                     float* __restrict__ out) {
    const int d = blockIdx.x;
    const int start = offsets[d];
    const int cnt = counts[d];
    const int t = threadIdx.x;
    const int q = t & 31;   // 4-float chunk index: dims [4q, 4q+4)
    const int g = t >> 5;   // node group 0..15

    __shared__ int sidx[1024];

    const float* xq = x + (size_t)q * 4;
    f32x4 a0 = {0.f, 0.f, 0.f, 0.f};
    f32x4 a1 = a0, a2 = a0, a3 = a0;

    for (int base = 0; base < cnt; base += 1024) {
        const int m = min(cnt - base, 1024);
        for (int i = t; i < m; i += 512) sidx[i] = sorted[start + base + i];
        __syncthreads();

        int n = g;
        for (; n + 3 * NG < m; n += 4 * NG) {
            int i0 = sidx[n];
            int i1 = sidx[n + NG];
            int i2 = sidx[n + 2 * NG];
            int i3 = sidx[n + 3 * NG];
            f32x4 v0 = __builtin_nontemporal_load(
                (const f32x4*)(xq + (size_t)i0 * DIM_IN));
            f32x4 v1 = __builtin_nontemporal_load(
                (const f32x4*)(xq + (size_t)i1 * DIM_IN));
            f32x4 v2 = __builtin_nontemporal_load(
                (const f32x4*)(xq + (size_t)i2 * DIM_IN));
            f32x4 v3 = __builtin_nontemporal_load(
                (const f32x4*)(xq + (size_t)i3 * DIM_IN));
            a0 += v0; a1 += v1; a2 += v2; a3 += v3;
        }
        for (; n < m; n += NG) {
            int i0 = sidx[n];
            f32x4 v0 = __builtin_nontemporal_load(
                (const f32x4*)(xq + (size_t)i0 * DIM_IN));
            a0 += v0;
        }
        __syncthreads();   // protect sidx before next chunk refill
    }

    a0 += a1 + a2 + a3;

    __shared__ float part[NG][DIM_IN];
    part[g][q * 4 + 0] = a0.x;
    part[g][q * 4 + 1] = a0.y;
    part[g][q * 4 + 2] = a0.z;
    part[g][q * 4 + 3] = a0.w;
    __syncthreads();

    __shared__ float hrelu[DIM_IN];
    if (t < DIM_IN) {
        float s = 0.f;
#pragma unroll
        for (int gg = 0; gg < NG; gg++) s += part[gg][t];
        hrelu[t] = fmaxf(s, 0.f);
    }
    __syncthreads();

    // layer 1: h1[c] = relu(b1[c] + sum_k hrelu[k]*w1[k,c]); w1 [128,256]
    // split k-range in 2 halves across the 512 threads
    {
        const int c = t & 255;
        const int h = t >> 8;      // 0..1
        float s1 = 0.f;
        const int k0 = h * 64;
#pragma unroll 8
        for (int k = k0; k < k0 + 64; k++) {
            s1 = fmaf(hrelu[k], w1[k * DIM_HID + c], s1);
        }
        __shared__ float p1[2][DIM_HID];
        p1[h][c] = s1;
        __syncthreads();
        __shared__ float h1s[DIM_HID];
        if (t < DIM_HID) h1s[t] = fmaxf(b1[t] + p1[0][t] + p1[1][t], 0.f);
        __syncthreads();

        // layer 2: out[c2] = b2[c2] + sum_j h1[j]*w2[j,c2]; w2 [256,128]
        // split j-range in 4 quarters across the 512 threads
        const int c2 = t & 127;
        const int hh = t >> 7;     // 0..3
        float s2 = 0.f;
        const int j0 = hh * 64;
#pragma unroll 8
        for (int j = j0; j < j0 + 64; j++) {
            s2 = fmaf(h1s[j], w2[j * DIM_OUT + c2], s2);
        }
        __shared__ float p2[4][DIM_OUT];
        p2[hh][c2] = s2;
        __syncthreads();
        if (t < DIM_OUT)
            out[d * DIM_OUT + t] =
                b2[t] + p2[0][t] + p2[1][t] + p2[2][t] + p2[3][t];
    }
}

extern "C" void kernel_launch(void* const* d_in, const int* in_sizes, int n_in,
                              void* d_out, int out_size, void* d_ws, size_t ws_size,
                              hipStream_t stream) {
    const float* x    = (const float*)d_in[0];
    const int*   zone = (const int*)d_in[1];
    const float* w1   = (const float*)d_in[2];
    const float* b1   = (const float*)d_in[3];
    const float* w2   = (const float*)d_in[4];
    const float* b2   = (const float*)d_in[5];
    float* out = (float*)d_out;
    int n = in_sizes[0] / DIM_IN;   // 500000 nodes

    char* ws = (char*)d_ws;
    int* counts    = (int*)(ws);
    int* offsets   = (int*)(ws + 4096);
    int* bar       = (int*)(ws + 8192);
    int* blockHist = (int*)(ws + 65536);
    int* sorted    = (int*)(ws + (2u << 20));

    // barrier counter must start at 0 (workspace is poisoned between runs)
    hipMemsetAsync(bar, 0, 64, stream);

    sort_kernel<<<NB, 256, 0, stream>>>(zone, n, blockHist, counts,
                                        offsets, sorted, bar);
    district_kernel<<<N_DIST, 512, 0, stream>>>(x, sorted, offsets, counts,
                                                w1, b1, w2, b2, out);
}

// Round 5
// 382.303 us; speedup vs baseline: 1.3229x; 1.1387x over previous
//
#include <hip/hip_runtime.h>

#define DIM_IN 128
#define DIM_HID 256
#define DIM_OUT 128
#define N_DIST 1024
#define NB 256          // blocks for hist/scatter (chunked counting sort)

// ws layout (bytes):
// [0,      4096): counts[1024]
// [4096,   8192): offsets[1024]   (written by scatter block 0, read by district)
// [65536, 65536+1MB): blockHist -> rewritten in place by scanA to per-district
//                     exclusive block starts (WITHOUT global offset)
// [2MB,    4MB): sorted node indices [N] int32
// [4MB,    5MB): zid[N] ushort — decoded district ids (hist writes, scatter reads)
//
// No global atomics anywhere: deterministic counting sort.

__device__ __forceinline__ int detect_is64(const int* __restrict__ zone_raw,
                                           int t, int* s_flag) {
    // int64 zone_lst => high words all zero. Checked by wave 0 via ballot.
    if (t < 64) {
        bool hi_zero = (zone_raw[2 * t + 1] == 0);
        unsigned long long m = __ballot(hi_zero);
        if (t == 0) *s_flag = (m == ~0ull) ? 1 : 0;
    }
    __syncthreads();
    return *s_flag;
}

__global__ __launch_bounds__(256)
void hist_kernel(const int* __restrict__ zone, int n,
                 int* __restrict__ blockHist,
                 unsigned short* __restrict__ zid) {
    __shared__ int lhist[N_DIST];
    __shared__ int s_is64;
    const int t = threadIdx.x;
    const int b = blockIdx.x;
    for (int i = t; i < N_DIST; i += 256) lhist[i] = 0;
    const int is64 = detect_is64(zone, t, &s_is64);   // has __syncthreads inside

    const int chunk = (n + NB - 1) / NB;
    const int start = b * chunk;
    const int end = min(n, start + chunk);
    const long long* zone64 = (const long long*)zone;
    for (int i = start + t; i < end; i += 256) {
        int z = is64 ? (int)zone64[i] : zone[i];
        zid[i] = (unsigned short)z;          // cache decoded id for scatter
        atomicAdd(&lhist[z], 1);             // LDS atomic only
    }
    __syncthreads();
    for (int i = t; i < N_DIST; i += 256) blockHist[b * N_DIST + i] = lhist[i];
}

// Parallel per-district prefix over the NB block histograms.
// 256 blocks x 4 waves; each wave owns one district d. Lane l holds
// blocks 4l..4l+3 (NB=256 = 4*64). In-place rewrite of blockHist[b][d]
// into the district-local exclusive start (global offset added in scatter).
// Strided column reads are L2-absorbed (blockHist = 1MB, each 64B line
// reused by 16 threads) — not an HBM over-fetch.
__global__ __launch_bounds__(256)
void scanA_kernel(int* __restrict__ blockHist, int* __restrict__ counts) {
    const int t = threadIdx.x;
    const int lane = t & 63;
    const int w = t >> 6;
    const int d = blockIdx.x * 4 + w;

    int v0 = blockHist[(4 * lane + 0) * N_DIST + d];
    int v1 = blockHist[(4 * lane + 1) * N_DIST + d];
    int v2 = blockHist[(4 * lane + 2) * N_DIST + d];
    int v3 = blockHist[(4 * lane + 3) * N_DIST + d];
    const int tsum = v0 + v1 + v2 + v3;

    int s = tsum;                       // inclusive wave scan of per-lane sums
#pragma unroll
    for (int off = 1; off < 64; off <<= 1) {
        int u = __shfl_up(s, off);
        if (lane >= off) s += u;
    }
    const int total = __shfl(s, 63);
    int excl = s - tsum;                // exclusive start for lane's first block

    blockHist[(4 * lane + 0) * N_DIST + d] = excl; excl += v0;
    blockHist[(4 * lane + 1) * N_DIST + d] = excl; excl += v1;
    blockHist[(4 * lane + 2) * N_DIST + d] = excl; excl += v2;
    blockHist[(4 * lane + 3) * N_DIST + d] = excl;

    if (lane == 0) counts[d] = total;
}

// Scatter, with the offsets scan (over counts[1024]) computed redundantly
// per block in LDS: int4 load + wave shfl scan + cross-wave combine.
// Reads cached ushort district ids (1MB) instead of re-decoding the 4MB
// int64 zone array. Block 0 publishes offsets[] for the district kernel.
__global__ __launch_bounds__(256)
void scatter_kernel(int n,
                    const int* __restrict__ blockStart,
                    const int* __restrict__ counts,
                    const unsigned short* __restrict__ zid,
                    int* __restrict__ offsets,
                    int* __restrict__ sorted) {
    __shared__ int off[N_DIST];
    __shared__ int lcur[N_DIST];
    __shared__ int wsum[4];
    const int t = threadIdx.x;
    const int b = blockIdx.x;
    const int lane = t & 63;
    const int w = t >> 6;

    // exclusive scan of counts[1024]: thread t owns counts[4t..4t+3]
    int4 c4 = ((const int4*)counts)[t];
    const int tsum = c4.x + c4.y + c4.z + c4.w;
    int s = tsum;
#pragma unroll
    for (int o = 1; o < 64; o <<= 1) {
        int u = __shfl_up(s, o);
        if (lane >= o) s += u;
    }
    if (lane == 63) wsum[w] = s;
    __syncthreads();
    int wbase = 0;
#pragma unroll
    for (int ww = 0; ww < 3; ww++) wbase += (ww < w) ? wsum[ww] : 0;
    int excl = wbase + s - tsum;
    off[4 * t + 0] = excl;
    off[4 * t + 1] = excl + c4.x;
    off[4 * t + 2] = excl + c4.x + c4.y;
    off[4 * t + 3] = excl + c4.x + c4.y + c4.z;
    __syncthreads();

    for (int i = t; i < N_DIST; i += 256)
        lcur[i] = off[i] + blockStart[b * N_DIST + i];
    if (b == 0)
        for (int i = t; i < N_DIST; i += 256) offsets[i] = off[i];
    __syncthreads();

    const int chunk = (n + NB - 1) / NB;
    const int start = b * chunk;
    const int end = min(n, start + chunk);
    for (int i = start + t; i < end; i += 256) {
        int z = zid[i];
        int pos = atomicAdd(&lcur[z], 1);   // LDS atomic only
        sorted[pos] = i;
    }
}

// One block (512 threads) per district: 16 node-groups x 32 lanes gather
// float4 rows; staged sorted indices in LDS; reduce to head[128]; fused MLP
// with both linear layers split across all 512 threads (LDS partial combine).
#define NG 16
__global__ __launch_bounds__(512)
void district_kernel(const float* __restrict__ x, const int* __restrict__ sorted,
                     const int* __restrict__ offsets, const int* __restrict__ counts,
                     const float* __restrict__ w1, const float* __restrict__ b1,
                     const float* __restrict__ w2, const float* __restrict__ b2,
                     float* __restrict__ out) {
    const int d = blockIdx.x;
    const int start = offsets[d];
    const int cnt = counts[d];
    const int t = threadIdx.x;
    const int q = t & 31;   // 4-float chunk index: dims [4q, 4q+4)
    const int g = t >> 5;   // node group 0..15

    __shared__ int sidx[1024];

    const float* xq = x + (size_t)q * 4;
    float4 a0 = make_float4(0.f, 0.f, 0.f, 0.f);
    float4 a1 = a0, a2 = a0, a3 = a0;

    for (int base = 0; base < cnt; base += 1024) {
        const int m = min(cnt - base, 1024);
        for (int i = t; i < m; i += 512) sidx[i] = sorted[start + base + i];
        __syncthreads();

        int n = g;
        for (; n + 3 * NG < m; n += 4 * NG) {
            int i0 = sidx[n];
            int i1 = sidx[n + NG];
            int i2 = sidx[n + 2 * NG];
            int i3 = sidx[n + 3 * NG];
            float4 v0 = *(const float4*)(xq + (size_t)i0 * DIM_IN);
            float4 v1 = *(const float4*)(xq + (size_t)i1 * DIM_IN);
            float4 v2 = *(const float4*)(xq + (size_t)i2 * DIM_IN);
            float4 v3 = *(const float4*)(xq + (size_t)i3 * DIM_IN);
            a0.x += v0.x; a0.y += v0.y; a0.z += v0.z; a0.w += v0.w;
            a1.x += v1.x; a1.y += v1.y; a1.z += v1.z; a1.w += v1.w;
            a2.x += v2.x; a2.y += v2.y; a2.z += v2.z; a2.w += v2.w;
            a3.x += v3.x; a3.y += v3.y; a3.z += v3.z; a3.w += v3.w;
        }
        for (; n < m; n += NG) {
            int i0 = sidx[n];
            float4 v0 = *(const float4*)(xq + (size_t)i0 * DIM_IN);
            a0.x += v0.x; a0.y += v0.y; a0.z += v0.z; a0.w += v0.w;
        }
        __syncthreads();   // protect sidx before next chunk refill
    }

    a0.x += a1.x + a2.x + a3.x;
    a0.y += a1.y + a2.y + a3.y;
    a0.z += a1.z + a2.z + a3.z;
    a0.w += a1.w + a2.w + a3.w;

    __shared__ float part[NG][DIM_IN];
    part[g][q * 4 + 0] = a0.x;
    part[g][q * 4 + 1] = a0.y;
    part[g][q * 4 + 2] = a0.z;
    part[g][q * 4 + 3] = a0.w;
    __syncthreads();

    __shared__ float hrelu[DIM_IN];
    if (t < DIM_IN) {
        float s = 0.f;
#pragma unroll
        for (int gg = 0; gg < NG; gg++) s += part[gg][t];
        hrelu[t] = fmaxf(s, 0.f);
    }
    __syncthreads();

    // layer 1: h1[c] = relu(b1[c] + sum_k hrelu[k]*w1[k,c]); w1 [128,256]
    // split k-range in 2 halves across the 512 threads
    {
        const int c = t & 255;
        const int h = t >> 8;      // 0..1
        float s1 = 0.f;
        const int k0 = h * 64;
#pragma unroll 8
        for (int k = k0; k < k0 + 64; k++) {
            s1 = fmaf(hrelu[k], w1[k * DIM_HID + c], s1);
        }
        __shared__ float p1[2][DIM_HID];
        p1[h][c] = s1;
        __syncthreads();
        __shared__ float h1s[DIM_HID];
        if (t < DIM_HID) h1s[t] = fmaxf(b1[t] + p1[0][t] + p1[1][t], 0.f);
        __syncthreads();

        // layer 2: out[c2] = b2[c2] + sum_j h1[j]*w2[j,c2]; w2 [256,128]
        // split j-range in 4 quarters across the 512 threads
        const int c2 = t & 127;
        const int hh = t >> 7;     // 0..3
        float s2 = 0.f;
        const int j0 = hh * 64;
#pragma unroll 8
        for (int j = j0; j < j0 + 64; j++) {
            s2 = fmaf(h1s[j], w2[j * DIM_OUT + c2], s2);
        }
        __shared__ float p2[4][DIM_OUT];
        p2[hh][c2] = s2;
        __syncthreads();
        if (t < DIM_OUT)
            out[d * DIM_OUT + t] =
                b2[t] + p2[0][t] + p2[1][t] + p2[2][t] + p2[3][t];
    }
}

extern "C" void kernel_launch(void* const* d_in, const int* in_sizes, int n_in,
                              void* d_out, int out_size, void* d_ws, size_t ws_size,
                              hipStream_t stream) {
    const float* x    = (const float*)d_in[0];
    const int*   zone = (const int*)d_in[1];
    const float* w1   = (const float*)d_in[2];
    const float* b1   = (const float*)d_in[3];
    const float* w2   = (const float*)d_in[4];
    const float* b2   = (const float*)d_in[5];
    float* out = (float*)d_out;
    const int n = in_sizes[0] / DIM_IN;   // 500000 nodes

    char* ws = (char*)d_ws;
    int* counts    = (int*)(ws);
    int* offsets   = (int*)(ws + 4096);
    int* blockHist = (int*)(ws + 65536);
    int* sorted    = (int*)(ws + (2u << 20));
    unsigned short* zid = (unsigned short*)(ws + (4u << 20));

    hist_kernel<<<NB, 256, 0, stream>>>(zone, n, blockHist, zid);
    scanA_kernel<<<N_DIST / 4, 256, 0, stream>>>(blockHist, counts);
    scatter_kernel<<<NB, 256, 0, stream>>>(n, blockHist, counts, zid,
                                           offsets, sorted);
    district_kernel<<<N_DIST, 512, 0, stream>>>(x, sorted, offsets, counts,
                                                w1, b1, w2, b2, out);
}